// Round 7
// baseline (205.604 us; speedup 1.0000x reference)
//
#include <hip/hip_runtime.h>
#include <cstdint>

typedef unsigned short u16;
typedef __bf16 bf16x8 __attribute__((ext_vector_type(8)));
typedef float f32x4 __attribute__((ext_vector_type(4)));

#define M_DIM 8192
#define N_DIM 1024
#define I_DIM 1024
#define NDEG 8                    /* stored degrees d=1..8 */
#define K_DIM (I_DIM * NDEG)      /* 8192 */
#define BM 256
#define BN 128
#define BK 32
#define NT (K_DIM / BK)           /* 256 K-tiles */
#define A_TILE (BM * BK)          /* 8192 u16 = 16 KB */
#define B_TILE (BN * BK)          /* 4096 u16 = 8 KB  */

__device__ __forceinline__ u16 f2bf(float f) {
    union { float f; uint32_t u; } v; v.f = f;
    return (u16)((v.u + 0x7FFFu + ((v.u >> 16) & 1u)) >> 16);
}

__device__ __forceinline__ void gload_lds16(const u16* g, u16* l) {
    auto lp = reinterpret_cast<__attribute__((address_space(3))) uint32_t*>(
        reinterpret_cast<uintptr_t>(l));
    __builtin_amdgcn_global_load_lds(reinterpret_cast<const uint32_t*>(g), lp, 16, 0, 0);
}

// ---------------------------------------------------------------------------
// Kernel 1: LDS-transposed transform.
//   Bt[o][i*8+d'] = (bf16) coeffs[i][o][1+d'],  bias[o] += sum_i coeffs[i][o][0]
// ---------------------------------------------------------------------------
__global__ __launch_bounds__(256) void aw_transform(
    const float* __restrict__ coeffs, u16* __restrict__ Bt, float* __restrict__ bias)
{
    __shared__ float lds[32][292];
    int bi = blockIdx.x >> 5, bo = blockIdx.x & 31;
    int i0 = bi * 32, o0 = bo * 32;
    int t = threadIdx.x;

    {
        int r = t >> 3, s = t & 7;
        const float4* src = (const float4*)(coeffs + ((size_t)(i0 + r) * N_DIM + o0) * 9);
#pragma unroll
        for (int j = 0; j < 9; ++j) {
            float4 v = src[s * 9 + j];
            *(float4*)&lds[r][(s * 9 + j) * 4] = v;
        }
    }
    __syncthreads();

    {
        int c = t >> 3, s2 = t & 7;
        u16 ob[32];
#pragma unroll
        for (int rr = 0; rr < 4; ++rr)
#pragma unroll
            for (int dd = 0; dd < 8; ++dd)
                ob[rr * 8 + dd] = f2bf(lds[s2 * 4 + rr][c * 9 + 1 + dd]);
        uint4* dst = (uint4*)(Bt + (size_t)(o0 + c) * K_DIM + (size_t)i0 * 8 + s2 * 32);
        const uint4* sp = (const uint4*)ob;
#pragma unroll
        for (int u = 0; u < 4; ++u) dst[u] = sp[u];
    }

    if (t < 32) {
        float sum = 0.f;
#pragma unroll
        for (int rr = 0; rr < 32; ++rr) sum += lds[rr][t * 9];
        atomicAdd(&bias[o0 + t], sum);
    }
}

// ---------------------------------------------------------------------------
// Kernel 2: A[rb][i*8+d'] = (bf16) basis_{1+d'}(x[row0+rb][i]) ; 8 i's/thread
// ---------------------------------------------------------------------------
__global__ void aw_basis(const float* __restrict__ x,
                         const float* __restrict__ pa, const float* __restrict__ pb,
                         const float* __restrict__ pc, const float* __restrict__ pd,
                         const float* __restrict__ pq,
                         u16* __restrict__ A, int row0)
{
    int t  = blockIdx.x * 256 + threadIdx.x;
    int rb = t >> 7;
    int g  = t & 127;
    int i0 = g << 3;
    int b  = row0 + rb;

    float a = *pa, bb = *pb, c = *pc, d = *pd, q = *pq;
    float ab = a * bb, cd = c * d, abcd = ab * cd;

    float qp[17];
    qp[0] = 1.f;
#pragma unroll
    for (int k = 1; k <= 16; ++k) qp[k] = qp[k - 1] * q;

    float den1 = 1.f + abcd * q * q;
    float c1x = 2.f * (1.f + ab * q) / den1;
    float c1c = -(a + bb) * (1.f + cd * q) / den1;

    float An[9], Cn[9], Sn[9];
#pragma unroll
    for (int n = 2; n <= 8; ++n) {
        float t1 = 1.f - ab * qp[n - 1];
        float t2 = 1.f - cd * qp[n - 1];
        float t3 = 1.f - abcd * qp[2 * n - 2];
        float t4 = 1.f - abcd * qp[2 * n - 1];
        float t5 = 1.f - abcd * qp[2 * n];
        An[n] = (t1 * t2 * t3) / (t4 * t5);
        Cn[n] = ((1.f - qp[n]) * t1 * t2 * t3) / (t3 * t4);
        Sn[n] = 1.f / (1.f - qp[n]);
    }

    const float4* x4 = (const float4*)(x + (size_t)b * I_DIM + i0);
    float4 v0 = x4[0], v1 = x4[1];
    float xv[8] = {v0.x, v0.y, v0.z, v0.w, v1.x, v1.y, v1.z, v1.w};

    u16 ob[64];
#pragma unroll
    for (int j = 0; j < 8; ++j) {
        float xj = xv[j];
        float p1 = c1x * xj + c1c;
        ob[j * 8 + 0] = f2bf(p1);
        float pm2 = 1.f, pm1 = p1;
#pragma unroll
        for (int n = 2; n <= 8; ++n) {
            float pn = ((2.f * xj - An[n]) * pm1 - Cn[n] * pm2) * Sn[n];
            ob[j * 8 + n - 1] = f2bf(pn);
            pm2 = pm1; pm1 = pn;
        }
    }

    uint4* dst = (uint4*)(A + (size_t)rb * K_DIM + (size_t)i0 * 8);
    const uint4* s = (const uint4*)ob;
#pragma unroll
    for (int u = 0; u < 8; ++u) dst[u] = s[u];
}

// ---------------------------------------------------------------------------
// Kernel 3: register-read-ahead pipelined GEMM.
// BM=256 x BN=128, BK=32, 512 thr (8 waves 4Mx2N, 64x64/wave, acc 4x4).
// QUAD-buffered LDS (96 KiB), stage depth 3, fragment regs double-buffered:
// per tile t: [stage S(t+3); read R(t+1) frags -> regs; MFMA on frags[t];
// vmcnt(3); barrier]. Race-free by construction:
//  - R(t+1) after barrier@t-1 which (via vmcnt(3)@t-1) guarantees S(t+1)
//    landed for ALL waves (in-order vmcnt retirement, 3 loads/stage).
//  - S(t+3) writes buf[(t+3)&3]=buf[(t-1)&3]; its last readers R(t-1) were
//    drained (compiler lgkmcnt) before each wave's MFMA@t-1, which precedes
//    barrier@t-1, which precedes S(t+3)@t.
// LDS-read XOR swizzle for 64B rows: slot = s ^ (r&3) ^ ((r>>2)&3) -> 2-way
// max (free, m136); staging source pre-swizzled with the same involution.
// T1 XCD swizzle, T5 setprio.
// ---------------------------------------------------------------------------
__global__ __launch_bounds__(512, 2) void aw_gemm(
    const u16* __restrict__ A,
    const u16* __restrict__ B,
    const float* __restrict__ bias,
    float* __restrict__ C,
    int row0, int rowBlocks)
{
    __shared__ alignas(16) u16 As[4 * A_TILE];   // 64 KB
    __shared__ alignas(16) u16 Bs[4 * B_TILE];   // 32 KB

    int nwg = rowBlocks * 8;
    int bid = blockIdx.x;
    int per = nwg >> 3;
    int logical = (bid & 7) * per + (bid >> 3);
    int rowBlk = logical >> 3;       // 8 col-blocks
    int colBlk = logical & 7;

    const int tid  = threadIdx.x;
    const int lane = tid & 63;
    const int wid  = tid >> 6;
    const int wr = wid & 3;          // 4 M-waves
    const int wc = wid >> 2;         // 2 N-waves

    // --- staging addresses: 2 A-loads + 1 B-load per thread per tile ---
    // idx covers 16B slot: row r = idx>>2, slot sl = idx&3;
    // source col pre-swizzled: slot' = sl ^ (r&3) ^ ((r>>2)&3)
    const u16 *gA0, *gA1, *gB0;
    int ldsA0, ldsA1, ldsB0;
    {
        const size_t aBase = (size_t)rowBlk * BM * K_DIM;
        const size_t bBase = (size_t)colBlk * BN * K_DIM;
        int idx = tid;                       // A, j=0
        int r = idx >> 2, sl = idx & 3;
        gA0 = A + aBase + (size_t)r * K_DIM + (((sl ^ (r & 3) ^ ((r >> 2) & 3)) & 3) << 3);
        ldsA0 = idx << 3;
        idx = 512 + tid;                     // A, j=1
        r = idx >> 2; sl = idx & 3;
        gA1 = A + aBase + (size_t)r * K_DIM + (((sl ^ (r & 3) ^ ((r >> 2) & 3)) & 3) << 3);
        ldsA1 = idx << 3;
        idx = tid;                           // B
        r = idx >> 2; sl = idx & 3;
        gB0 = B + bBase + (size_t)r * K_DIM + (((sl ^ (r & 3) ^ ((r >> 2) & 3)) & 3) << 3);
        ldsB0 = idx << 3;
    }

    // --- fragment byte-offsets (swizzled reads), row = 64B ---
    int offA[4], offB[4];
#pragma unroll
    for (int mi = 0; mi < 4; ++mi) {
        int r = wr * 64 + mi * 16 + (lane & 15);
        int s = lane >> 4;
        offA[mi] = r * 64 + (((s ^ (r & 3) ^ ((r >> 2) & 3)) & 3) << 4);
    }
#pragma unroll
    for (int ni = 0; ni < 4; ++ni) {
        int r = wc * 64 + ni * 16 + (lane & 15);
        int s = lane >> 4;
        offB[ni] = r * 64 + (((s ^ (r & 3) ^ ((r >> 2) & 3)) & 3) << 4);
    }

    f32x4 acc[4][4];
#pragma unroll
    for (int mi = 0; mi < 4; ++mi)
#pragma unroll
        for (int ni = 0; ni < 4; ++ni)
            acc[mi][ni] = (f32x4){0.f, 0.f, 0.f, 0.f};

    auto stage = [&](int kt, int buf) {
        const int k0 = kt * BK;
        u16* dA = As + buf * A_TILE;
        u16* dB = Bs + buf * B_TILE;
        gload_lds16(gA0 + k0, dA + ldsA0);
        gload_lds16(gA1 + k0, dA + ldsA1);
        gload_lds16(gB0 + k0, dB + ldsB0);
    };
    auto rdfrags = [&](bf16x8 (&fa)[4], bf16x8 (&fb)[4], int buf) {
        const char* aB = (const char*)(As + buf * A_TILE);
        const char* bB = (const char*)(Bs + buf * B_TILE);
#pragma unroll
        for (int mi = 0; mi < 4; ++mi) fa[mi] = *(const bf16x8*)(aB + offA[mi]);
#pragma unroll
        for (int ni = 0; ni < 4; ++ni) fb[ni] = *(const bf16x8*)(bB + offB[ni]);
    };
    auto domfma = [&](bf16x8 (&fa)[4], bf16x8 (&fb)[4]) {
        __builtin_amdgcn_s_setprio(1);
#pragma unroll
        for (int mi = 0; mi < 4; ++mi)
#pragma unroll
            for (int ni = 0; ni < 4; ++ni)
                acc[mi][ni] = __builtin_amdgcn_mfma_f32_16x16x32_bf16(
                    fa[mi], fb[ni], acc[mi][ni], 0, 0, 0);
        __builtin_amdgcn_s_setprio(0);
    };

#define TILE(CURA, CURB, NXTA, NXTB, T, DOS, DOR, VM)                         \
    do {                                                                      \
        if (DOS) stage((T) + 3, ((T) + 3) & 3);                               \
        if (DOR) rdfrags(NXTA, NXTB, ((T) + 1) & 3);                          \
        domfma(CURA, CURB);                                                   \
        if ((VM) == 3) asm volatile("s_waitcnt vmcnt(3)" ::: "memory");       \
        else if ((VM) == 0) asm volatile("s_waitcnt vmcnt(0)" ::: "memory");  \
        __builtin_amdgcn_s_barrier();                                         \
    } while (0)

    // prologue: stage 3 tiles (9 loads); drain S(0),S(1); read frags[0]
    stage(0, 0); stage(1, 1); stage(2, 2);
    asm volatile("s_waitcnt vmcnt(3)" ::: "memory");
    __builtin_amdgcn_s_barrier();

    bf16x8 fa0[4], fb0[4], fa1[4], fb1[4];
    rdfrags(fa0, fb0, 0);

    for (int t = 0; t < NT - 4; t += 2) {       // t = 0 .. 250
        TILE(fa0, fb0, fa1, fb1, t,     true,  true, 3);
        TILE(fa1, fb1, fa0, fb0, t + 1, true,  true, 3);
    }
    TILE(fa0, fb0, fa1, fb1, NT - 4, true,  true, 3);    // t=252, S(255)
    TILE(fa1, fb1, fa0, fb0, NT - 3, false, true, 0);    // t=253
    TILE(fa0, fb0, fa1, fb1, NT - 2, false, true, -1);   // t=254
    domfma(fa1, fb1);                                    // t=255
#undef TILE

    // epilogue: D layout col=lane&15, row=(lane>>4)*4+j  [m89]
    int gRow = row0 + rowBlk * BM + wr * 64;
    int gCol = colBlk * BN + wc * 64;
#pragma unroll
    for (int mi = 0; mi < 4; ++mi) {
#pragma unroll
        for (int ni = 0; ni < 4; ++ni) {
            int rr = gRow + mi * 16 + ((lane >> 4) << 2);
            int cc = gCol + ni * 16 + (lane & 15);
            float bv = bias[cc];
            float* dst = C + (size_t)rr * N_DIM + cc;
#pragma unroll
            for (int j = 0; j < 4; ++j) dst[(size_t)j * N_DIM] = acc[mi][ni][j] + bv;
        }
    }
}

// ---------------------------------------------------------------------------
extern "C" void kernel_launch(void* const* d_in, const int* in_sizes, int n_in,
                              void* d_out, int out_size, void* d_ws, size_t ws_size,
                              hipStream_t stream)
{
    const float* x      = (const float*)d_in[0];
    const float* pa     = (const float*)d_in[1];
    const float* pb     = (const float*)d_in[2];
    const float* pc     = (const float*)d_in[3];
    const float* pd     = (const float*)d_in[4];
    const float* pq     = (const float*)d_in[5];
    const float* coeffs = (const float*)d_in[6];
    float* out = (float*)d_out;

    float* bias = (float*)d_ws;
    const size_t biasBytes = 4096;
    u16* Bt = (u16*)((char*)d_ws + biasBytes);
    const size_t btBytes = (size_t)N_DIM * K_DIM * sizeof(u16);   // 16.8 MB
    u16* Abuf = (u16*)((char*)d_ws + biasBytes + btBytes);
    size_t used = biasBytes + btBytes;
    size_t avail = ws_size > used ? ws_size - used : 0;

    int chunk = M_DIM;
    while (chunk > 256 && (size_t)chunk * K_DIM * sizeof(u16) > avail) chunk >>= 1;

    hipMemsetAsync(bias, 0, N_DIM * sizeof(float), stream);
    aw_transform<<<1024, 256, 0, stream>>>(coeffs, Bt, bias);

    for (int row0 = 0; row0 < M_DIM; row0 += chunk) {
        aw_basis<<<(chunk * 128) / 256, 256, 0, stream>>>(x, pa, pb, pc, pd, pq, Abuf, row0);
        int rowBlocks = chunk / BM;
        aw_gemm<<<rowBlocks * 8, 512, 0, stream>>>(Abuf, Bt, bias, out, row0, rowBlocks);
    }
}

// Round 8
// 186.426 us; speedup vs baseline: 1.1029x; 1.1029x over previous
//
#include <hip/hip_runtime.h>
#include <cstdint>

typedef unsigned short u16;
typedef __bf16 bf16x8 __attribute__((ext_vector_type(8)));
typedef float f32x4 __attribute__((ext_vector_type(4)));

#define M_DIM 8192
#define N_DIM 1024
#define I_DIM 1024
#define NDEG 8                    /* stored degrees d=1..8 */
#define K_DIM (I_DIM * NDEG)      /* 8192 */
#define BM 256
#define BN 128
#define BK 64
#define NT (K_DIM / BK)           /* 128 K-tiles */
#define A_TILE (BM * BK)          /* 16384 u16 = 32 KB */
#define B_TILE (BN * BK)          /* 8192  u16 = 16 KB */

__device__ __forceinline__ u16 f2bf(float f) {
    union { float f; uint32_t u; } v; v.f = f;
    return (u16)((v.u + 0x7FFFu + ((v.u >> 16) & 1u)) >> 16);
}

__device__ __forceinline__ void gload_lds16(const u16* g, u16* l) {
    auto lp = reinterpret_cast<__attribute__((address_space(3))) uint32_t*>(
        reinterpret_cast<uintptr_t>(l));
    __builtin_amdgcn_global_load_lds(reinterpret_cast<const uint32_t*>(g), lp, 16, 0, 0);
}

// ---------------------------------------------------------------------------
// Kernel 1: LDS-transposed transform.
//   Bt[o][i*8+d'] = (bf16) coeffs[i][o][1+d'],  bias[o] += sum_i coeffs[i][o][0]
// ---------------------------------------------------------------------------
__global__ __launch_bounds__(256) void aw_transform(
    const float* __restrict__ coeffs, u16* __restrict__ Bt, float* __restrict__ bias)
{
    __shared__ float lds[32][292];
    int bi = blockIdx.x >> 5, bo = blockIdx.x & 31;
    int i0 = bi * 32, o0 = bo * 32;
    int t = threadIdx.x;

    {
        int r = t >> 3, s = t & 7;
        const float4* src = (const float4*)(coeffs + ((size_t)(i0 + r) * N_DIM + o0) * 9);
#pragma unroll
        for (int j = 0; j < 9; ++j) {
            float4 v = src[s * 9 + j];
            *(float4*)&lds[r][(s * 9 + j) * 4] = v;
        }
    }
    __syncthreads();

    {
        int c = t >> 3, s2 = t & 7;
        u16 ob[32];
#pragma unroll
        for (int rr = 0; rr < 4; ++rr)
#pragma unroll
            for (int dd = 0; dd < 8; ++dd)
                ob[rr * 8 + dd] = f2bf(lds[s2 * 4 + rr][c * 9 + 1 + dd]);
        uint4* dst = (uint4*)(Bt + (size_t)(o0 + c) * K_DIM + (size_t)i0 * 8 + s2 * 32);
        const uint4* sp = (const uint4*)ob;
#pragma unroll
        for (int u = 0; u < 4; ++u) dst[u] = sp[u];
    }

    if (t < 32) {
        float sum = 0.f;
#pragma unroll
        for (int rr = 0; rr < 32; ++rr) sum += lds[rr][t * 9];
        atomicAdd(&bias[o0 + t], sum);
    }
}

// ---------------------------------------------------------------------------
// Kernel 2: A[rb][i*8+d'] = (bf16) basis_{1+d'}(x[row0+rb][i]) ; 8 i's/thread
// ---------------------------------------------------------------------------
__global__ void aw_basis(const float* __restrict__ x,
                         const float* __restrict__ pa, const float* __restrict__ pb,
                         const float* __restrict__ pc, const float* __restrict__ pd,
                         const float* __restrict__ pq,
                         u16* __restrict__ A, int row0)
{
    int t  = blockIdx.x * 256 + threadIdx.x;
    int rb = t >> 7;
    int g  = t & 127;
    int i0 = g << 3;
    int b  = row0 + rb;

    float a = *pa, bb = *pb, c = *pc, d = *pd, q = *pq;
    float ab = a * bb, cd = c * d, abcd = ab * cd;

    float qp[17];
    qp[0] = 1.f;
#pragma unroll
    for (int k = 1; k <= 16; ++k) qp[k] = qp[k - 1] * q;

    float den1 = 1.f + abcd * q * q;
    float c1x = 2.f * (1.f + ab * q) / den1;
    float c1c = -(a + bb) * (1.f + cd * q) / den1;

    float An[9], Cn[9], Sn[9];
#pragma unroll
    for (int n = 2; n <= 8; ++n) {
        float t1 = 1.f - ab * qp[n - 1];
        float t2 = 1.f - cd * qp[n - 1];
        float t3 = 1.f - abcd * qp[2 * n - 2];
        float t4 = 1.f - abcd * qp[2 * n - 1];
        float t5 = 1.f - abcd * qp[2 * n];
        An[n] = (t1 * t2 * t3) / (t4 * t5);
        Cn[n] = ((1.f - qp[n]) * t1 * t2 * t3) / (t3 * t4);
        Sn[n] = 1.f / (1.f - qp[n]);
    }

    const float4* x4 = (const float4*)(x + (size_t)b * I_DIM + i0);
    float4 v0 = x4[0], v1 = x4[1];
    float xv[8] = {v0.x, v0.y, v0.z, v0.w, v1.x, v1.y, v1.z, v1.w};

    u16 ob[64];
#pragma unroll
    for (int j = 0; j < 8; ++j) {
        float xj = xv[j];
        float p1 = c1x * xj + c1c;
        ob[j * 8 + 0] = f2bf(p1);
        float pm2 = 1.f, pm1 = p1;
#pragma unroll
        for (int n = 2; n <= 8; ++n) {
            float pn = ((2.f * xj - An[n]) * pm1 - Cn[n] * pm2) * Sn[n];
            ob[j * 8 + n - 1] = f2bf(pn);
            pm2 = pm1; pm1 = pn;
        }
    }

    uint4* dst = (uint4*)(A + (size_t)rb * K_DIM + (size_t)i0 * 8);
    const uint4* s = (const uint4*)ob;
#pragma unroll
    for (int u = 0; u < 8; ++u) dst[u] = s[u];
}

// ---------------------------------------------------------------------------
// Kernel 3: K-paired free-flow GEMM (r5 geometry x r6 schedule).
// BM=256 x BN=128, BK=64, 512 thr = 8 waves: 4 quadrant-owners (2M x 2N,
// per-wave 128x64 = 8x4 frags) x 2 K-halves (wave's ks-half = 32 of BK=64).
// 12 ds_read_b128 per 32 MFMA -> LDS/tile = 96KB rd + 48KB wr = 1152 cyc
// < 1242 cyc MFMA: MFMA-bound. Triple-buffered LDS (144 KiB); free-flow
// interior, ONE counted vmcnt(6) + ONE barrier per K-tile (hazards as r6:
// staged-before-read via vmcnt+barrier; re-stage-after-read via MFMA
// consuming reads before the preceding barrier). Verified-conflict-free
// slot^(r&7) swizzle (pre-swizzled global source). K-half partials merged
// once via LDS at epilogue (r5-verified). T1 XCD swizzle, T5 setprio.
// ---------------------------------------------------------------------------
__global__ __launch_bounds__(512) void aw_gemm(
    const u16* __restrict__ A,
    const u16* __restrict__ B,
    const float* __restrict__ bias,
    float* __restrict__ C,
    int row0, int rowBlocks)
{
    __shared__ alignas(16) u16 smem[3 * A_TILE + 3 * B_TILE];   // 144 KB
    u16* As = smem;
    u16* Bs = smem + 3 * A_TILE;

    int nwg = rowBlocks * 8;
    int bid = blockIdx.x;
    int per = nwg >> 3;
    int logical = (bid & 7) * per + (bid >> 3);
    int rowBlk = logical >> 3;       // 8 col-blocks
    int colBlk = logical & 7;

    const int tid  = threadIdx.x;
    const int lane = tid & 63;
    const int wid  = tid >> 6;
    const int quad = wid & 3;        // 4 C-quadrants (2M x 2N)
    const int wr   = quad >> 1;      // 0..1 (128-row half)
    const int wc   = quad & 1;       // 0..1 (64-col half)
    const int myKs = wid >> 2;       // 0..1 (32-wide K half of each tile)

    // --- staging addresses (k0 added per tile); source slot pre-swizzled ---
    const u16* gA[4]; const u16* gB[2];
    int ldsA[4], ldsB[2];
#pragma unroll
    for (int j = 0; j < 4; ++j) {
        int idx = j * 512 + tid;
        int r = idx >> 3, sl = idx & 7;
        gA[j] = A + (size_t)rowBlk * BM * K_DIM + (size_t)r * K_DIM + ((sl ^ (r & 7)) << 3);
        ldsA[j] = idx << 3;
    }
#pragma unroll
    for (int j = 0; j < 2; ++j) {
        int idx = j * 512 + tid;
        int r = idx >> 3, sl = idx & 7;
        gB[j] = B + (size_t)colBlk * BN * K_DIM + (size_t)r * K_DIM + ((sl ^ (r & 7)) << 3);
        ldsB[j] = idx << 3;
    }

    // --- fragment byte-offsets for this wave's ks-half (swizzled reads) ---
    int offA[8], offB[4];
#pragma unroll
    for (int mi = 0; mi < 8; ++mi) {
        int r = wr * 128 + mi * 16 + (lane & 15);
        int s = myKs * 4 + (lane >> 4);
        offA[mi] = r * 128 + ((s ^ (r & 7)) << 4);
    }
#pragma unroll
    for (int ni = 0; ni < 4; ++ni) {
        int r = wc * 64 + ni * 16 + (lane & 15);
        int s = myKs * 4 + (lane >> 4);
        offB[ni] = r * 128 + ((s ^ (r & 7)) << 4);
    }

    f32x4 acc[8][4];
#pragma unroll
    for (int mi = 0; mi < 8; ++mi)
#pragma unroll
        for (int ni = 0; ni < 4; ++ni)
            acc[mi][ni] = (f32x4){0.f, 0.f, 0.f, 0.f};

    auto stage = [&](int kt, int buf) {
        const int k0 = kt * BK;
        u16* dA = As + buf * A_TILE;
        u16* dB = Bs + buf * B_TILE;
        gload_lds16(gA[0] + k0, dA + ldsA[0]);
        gload_lds16(gA[1] + k0, dA + ldsA[1]);
        gload_lds16(gA[2] + k0, dA + ldsA[2]);
        gload_lds16(gA[3] + k0, dA + ldsA[3]);
        gload_lds16(gB[0] + k0, dB + ldsB[0]);
        gload_lds16(gB[1] + k0, dB + ldsB[1]);
    };

    // prologue: 2 tiles in flight (12 loads), wait for tile 0
    stage(0, 0);
    stage(1, 1);
    asm volatile("s_waitcnt vmcnt(6)" ::: "memory");
    __builtin_amdgcn_s_barrier();

    int buf = 0;
    for (int t = 0; t < NT; ++t) {
        const char* aB = (const char*)(As + buf * A_TILE);
        const char* bB = (const char*)(Bs + buf * B_TILE);
        int nb = buf + 2; if (nb >= 3) nb -= 3;
        const bool pf = (t + 2 < NT);

        // fragment reads for this wave's ks-half; prefetch issue interleaved.
        bf16x8 fa[8], fb[4];
#pragma unroll
        for (int mi = 0; mi < 4; ++mi) fa[mi] = *(const bf16x8*)(aB + offA[mi]);
#pragma unroll
        for (int ni = 0; ni < 2; ++ni) fb[ni] = *(const bf16x8*)(bB + offB[ni]);
        if (pf) stage(t + 2, nb);
#pragma unroll
        for (int mi = 4; mi < 8; ++mi) fa[mi] = *(const bf16x8*)(aB + offA[mi]);
#pragma unroll
        for (int ni = 2; ni < 4; ++ni) fb[ni] = *(const bf16x8*)(bB + offB[ni]);

        __builtin_amdgcn_s_setprio(1);
#pragma unroll
        for (int mi = 0; mi < 8; ++mi)
#pragma unroll
            for (int ni = 0; ni < 4; ++ni)
                acc[mi][ni] = __builtin_amdgcn_mfma_f32_16x16x32_bf16(
                    fa[mi], fb[ni], acc[mi][ni], 0, 0, 0);
        __builtin_amdgcn_s_setprio(0);

        // single counted drain + single barrier per K-tile
        if (pf)              { asm volatile("s_waitcnt vmcnt(6)" ::: "memory"); }
        else if (t + 1 < NT) { asm volatile("s_waitcnt vmcnt(0)" ::: "memory"); }
        __builtin_amdgcn_s_barrier();

        buf += 1; if (buf >= 3) buf -= 3;
    }

    // ---- epilogue: merge K-half partials via LDS (128 KB of the 144) ----
    float* red = (float*)smem;
    if (myKs == 1) {
        f32x4* dst = (f32x4*)red + quad * 2048;   // 32 KB per quadrant
#pragma unroll
        for (int mi = 0; mi < 8; ++mi)
#pragma unroll
            for (int ni = 0; ni < 4; ++ni)
                dst[(mi * 4 + ni) * 64 + lane] = acc[mi][ni];
    }
    __syncthreads();
    if (myKs == 0) {
        const f32x4* src = (const f32x4*)red + quad * 2048;
#pragma unroll
        for (int mi = 0; mi < 8; ++mi)
#pragma unroll
            for (int ni = 0; ni < 4; ++ni) {
                f32x4 p = src[(mi * 4 + ni) * 64 + lane];
                acc[mi][ni] += p;
            }

        // D layout col=lane&15, row=(lane>>4)*4+j  [m89]
        int gRow = row0 + rowBlk * BM + wr * 128;
        int gCol = colBlk * BN + wc * 64;
#pragma unroll
        for (int mi = 0; mi < 8; ++mi) {
#pragma unroll
            for (int ni = 0; ni < 4; ++ni) {
                int rr = gRow + mi * 16 + ((lane >> 4) << 2);
                int cc = gCol + ni * 16 + (lane & 15);
                float bv = bias[cc];
                float* dst = C + (size_t)rr * N_DIM + cc;
#pragma unroll
                for (int j = 0; j < 4; ++j) dst[(size_t)j * N_DIM] = acc[mi][ni][j] + bv;
            }
        }
    }
}

// ---------------------------------------------------------------------------
extern "C" void kernel_launch(void* const* d_in, const int* in_sizes, int n_in,
                              void* d_out, int out_size, void* d_ws, size_t ws_size,
                              hipStream_t stream)
{
    const float* x      = (const float*)d_in[0];
    const float* pa     = (const float*)d_in[1];
    const float* pb     = (const float*)d_in[2];
    const float* pc     = (const float*)d_in[3];
    const float* pd     = (const float*)d_in[4];
    const float* pq     = (const float*)d_in[5];
    const float* coeffs = (const float*)d_in[6];
    float* out = (float*)d_out;

    float* bias = (float*)d_ws;
    const size_t biasBytes = 4096;
    u16* Bt = (u16*)((char*)d_ws + biasBytes);
    const size_t btBytes = (size_t)N_DIM * K_DIM * sizeof(u16);   // 16.8 MB
    u16* Abuf = (u16*)((char*)d_ws + biasBytes + btBytes);
    size_t used = biasBytes + btBytes;
    size_t avail = ws_size > used ? ws_size - used : 0;

    int chunk = M_DIM;
    while (chunk > 256 && (size_t)chunk * K_DIM * sizeof(u16) > avail) chunk >>= 1;

    hipMemsetAsync(bias, 0, N_DIM * sizeof(float), stream);
    aw_transform<<<1024, 256, 0, stream>>>(coeffs, Bt, bias);

    for (int row0 = 0; row0 < M_DIM; row0 += chunk) {
        aw_basis<<<(chunk * 128) / 256, 256, 0, stream>>>(x, pa, pb, pc, pd, pq, Abuf, row0);
        int rowBlocks = chunk / BM;
        aw_gemm<<<rowBlocks * 8, 512, 0, stream>>>(Abuf, Bt, bias, out, row0, rowBlocks);
    }
}